// Round 6
// baseline (2464.195 us; speedup 1.0000x reference)
//
#include <hip/hip_runtime.h>
#include <hip/hip_bf16.h>
#include <stdint.h>

// ---------------------------------------------------------------------------
// PlanetoidSCN: binarize -> bitmask features -> binary SpMM -> tiled GEMMs ->
// dense SpMM (atomics) -> fused combine.
//
// Workspace budget (crash fix R5): previous layout needed 288.0 MB > 256 MiB
// and faulted. Now: S0 lives in d_out (f32, exactly N0*128), bit buffers
// overlay the head of Ts (dead before Ts is live). Total ws = S1 + S2 + Ts
// = 256,000,000 B = 244.1 MiB.
// ---------------------------------------------------------------------------

__global__ __launch_bounds__(256) void k_bits_node(const float* __restrict__ X,
        ulonglong2* __restrict__ bits, int n)
{
    int wid = (blockIdx.x * 256 + threadIdx.x) >> 6;
    int lane = threadIdx.x & 63;
    if (wid >= n) return;
    const float* row = X + (size_t)wid * 128;
    unsigned long long m0 = __ballot(row[lane] != 0.0f);
    unsigned long long m1 = __ballot(row[lane + 64] != 0.0f);
    if (lane == 0) { bits[wid].x = m0; bits[wid].y = m1; }
}

__global__ __launch_bounds__(256) void k_bits_edge(const int* __restrict__ idx,
        const ulonglong2* __restrict__ nb, ulonglong2* __restrict__ outb, int n)
{
    int e = blockIdx.x * 256 + threadIdx.x;
    if (e >= n) return;
    ulonglong2 a = nb[idx[2 * e]];
    ulonglong2 b = nb[idx[2 * e + 1]];
    ulonglong2 r; r.x = a.x & b.x; r.y = a.y & b.y;
    outb[e] = r;
}

__global__ __launch_bounds__(256) void k_bits_tri(const int* __restrict__ idx,
        const ulonglong2* __restrict__ nb, ulonglong2* __restrict__ outb, int n)
{
    int e = blockIdx.x * 256 + threadIdx.x;
    if (e >= n) return;
    ulonglong2 a = nb[idx[3 * e]];
    ulonglong2 b = nb[idx[3 * e + 1]];
    ulonglong2 c = nb[idx[3 * e + 2]];
    ulonglong2 r; r.x = a.x & b.x & c.x; r.y = a.y & b.y & c.y;
    outb[e] = r;
}

// S[row] += val * bits(col): one wave per nnz, skip zero features.
__global__ __launch_bounds__(256) void k_spmm_bin(const int* __restrict__ rows,
        const int* __restrict__ cols, const float* __restrict__ vals,
        const ulonglong2* __restrict__ bits, float* __restrict__ S, int nnz)
{
    int nz = (blockIdx.x * 256 + threadIdx.x) >> 6;
    int lane = threadIdx.x & 63;
    if (nz >= nnz) return;
    int r = rows[nz], c = cols[nz];
    float v = vals[nz];
    ulonglong2 m = bits[c];
    float* out = S + (size_t)r * 128;
    if ((m.x >> lane) & 1ull) atomicAdd(out + lane, v);
    if ((m.y >> lane) & 1ull) atomicAdd(out + lane + 64, v);
}

// Out[row] += scale * val * X[col]: one wave per nnz, 2 floats/lane.
__global__ __launch_bounds__(256) void k_spmm_dense(const int* __restrict__ rows,
        const int* __restrict__ cols, const float* __restrict__ vals,
        const float* __restrict__ X, float* __restrict__ Out, int nnz, float scale)
{
    int nz = (blockIdx.x * 256 + threadIdx.x) >> 6;
    int lane = threadIdx.x & 63;
    if (nz >= nnz) return;
    int r = rows[nz], c = cols[nz];
    float v = vals[nz] * scale;
    const float2* xr = (const float2*)(X + (size_t)c * 128);
    float2 x = xr[lane];
    float* out = Out + (size_t)r * 128 + lane * 2;
    atomicAdd(out + 0, v * x.x);
    atomicAdd(out + 1, v * x.y);
}

// H[r] = (prelu?)(S[r] @ W^T + b) * scale (+ addsrc[r]); W row-major [128][128].
// 32 rows/block staged in LDS; thread = 4 outputs x 4 rows register tile.
// In-place safe: each block stages its own 32 rows to LDS before overwriting.
template<int PRELU, int ADDSRC>
__global__ __launch_bounds__(256) void k_gemm(const float* __restrict__ S,
        const float* __restrict__ W, const float* __restrict__ bias,
        const float* __restrict__ addsrc, const float* __restrict__ pw,
        float* __restrict__ H, int n_rows, float scale)
{
    __shared__ float Sl[32][128];   // 16 KB
    const int t = threadIdx.x;
    const int ot = t & 31, rt = t >> 5;
    const int o0 = ot * 4;
    const int row_base = blockIdx.x * 32;

    for (int i = t; i < 32 * 32; i += 256) {   // 32 rows x 32 float4
        int r = i >> 5, c = i & 31;
        int gr = row_base + r;
        float4 v = make_float4(0.f, 0.f, 0.f, 0.f);
        if (gr < n_rows) v = *(const float4*)(S + (size_t)gr * 128 + c * 4);
        *(float4*)(&Sl[r][c * 4]) = v;
    }
    __syncthreads();

    float acc[4][4];
#pragma unroll
    for (int j = 0; j < 4; ++j)
#pragma unroll
        for (int k = 0; k < 4; ++k) acc[j][k] = 0.f;

    for (int f0 = 0; f0 < 128; f0 += 4) {
        float4 wv[4], sv[4];
#pragma unroll
        for (int k = 0; k < 4; ++k)
            wv[k] = *(const float4*)(W + (size_t)(o0 + k) * 128 + f0);
#pragma unroll
        for (int j = 0; j < 4; ++j)
            sv[j] = *(const float4*)(&Sl[rt * 4 + j][f0]);
#pragma unroll
        for (int j = 0; j < 4; ++j)
#pragma unroll
            for (int k = 0; k < 4; ++k)
                acc[j][k] += sv[j].x * wv[k].x + sv[j].y * wv[k].y
                           + sv[j].z * wv[k].z + sv[j].w * wv[k].w;
    }

    float4 bv = *(const float4*)(bias + o0);
    float w = 0.0f;
    if (PRELU) w = pw[0];
#pragma unroll
    for (int j = 0; j < 4; ++j) {
        int gr = row_base + rt * 4 + j;
        if (gr >= n_rows) continue;
        float4 x;
        x.x = acc[j][0] + bv.x; x.y = acc[j][1] + bv.y;
        x.z = acc[j][2] + bv.z; x.w = acc[j][3] + bv.w;
        if (PRELU) {
            x.x = x.x >= 0.f ? x.x : w * x.x;
            x.y = x.y >= 0.f ? x.y : w * x.y;
            x.z = x.z >= 0.f ? x.z : w * x.z;
            x.w = x.w >= 0.f ? x.w : w * x.w;
        }
        x.x *= scale; x.y *= scale; x.z *= scale; x.w *= scale;
        if (ADDSRC) {
            const float4 a = *(const float4*)(addsrc + (size_t)gr * 128 + o0);
            x.x += a.x; x.y += a.y; x.z += a.z; x.w += a.w;
        }
        *(float4*)(H + (size_t)gr * 128 + o0) = x;
    }
}

extern "C" void kernel_launch(void* const* d_in, const int* in_sizes, int n_in,
                              void* d_out, int out_size, void* d_ws, size_t ws_size,
                              hipStream_t stream)
{
    const float* X0  = (const float*)d_in[0];
    const int*  eidx = (const int*)  d_in[1];
    const int*  tidx = (const int*)  d_in[2];
    const int* L0r = (const int*)d_in[3];
    const int* L0c = (const int*)d_in[4];
    const float* L0v = (const float*)d_in[5];
    const int* L1r = (const int*)d_in[6];
    const int* L1c = (const int*)d_in[7];
    const float* L1v = (const float*)d_in[8];
    const int* L2r = (const int*)d_in[9];
    const int* L2c = (const int*)d_in[10];
    const float* L2v = (const float*)d_in[11];
    const int* B1r = (const int*)d_in[12];
    const int* B1c = (const int*)d_in[13];
    const float* B1v = (const float*)d_in[14];
    const int* B2r = (const int*)d_in[15];
    const int* B2c = (const int*)d_in[16];
    const float* B2v = (const float*)d_in[17];
    const float* Wn   = (const float*)d_in[18];
    const float* bn   = (const float*)d_in[19];
    const float* We   = (const float*)d_in[20];
    const float* be   = (const float*)d_in[21];
    const float* Wt   = (const float*)d_in[22];
    const float* bt   = (const float*)d_in[23];
    const float* Wtri = (const float*)d_in[24];
    const float* btri = (const float*)d_in[25];
    const float* pw   = (const float*)d_in[26];

    const int N0 = in_sizes[0] / 128;
    const int N1 = in_sizes[1] / 2;
    const int N2 = in_sizes[2] / 3;
    const int nnz0 = in_sizes[3], nnz1 = in_sizes[6], nnz2 = in_sizes[9];
    const int nnzb1 = in_sizes[12], nnzb2 = in_sizes[15];

    // Workspace layout (244.1 MiB total):
    //   S1 [N1*128 f32] | S2 [N2*128 f32] | Ts [N1*128 f32]
    // Bit buffers (Xb/Eb/Tb, 6.4 MB) overlay the head of Ts — they are dead
    // before Ts is first zeroed/used. S0 lives in d_out (f32 N0*128).
    char* ws = (char*)d_ws;
    size_t off = 0;
    auto take = [&](size_t bytes) {
        void* p = ws + off;
        off += (bytes + 255) & ~(size_t)255;
        return p;
    };
    float* S1 = (float*)take((size_t)N1 * 512);
    float* S2 = (float*)take((size_t)N2 * 512);
    float* Ts = (float*)take((size_t)N1 * 512);
    ulonglong2* Xb = (ulonglong2*)Ts;                         // N0*16 = 0.8 MB
    ulonglong2* Eb = (ulonglong2*)((char*)Ts + (size_t)N0 * 16);   // 2.4 MB
    ulonglong2* Tb = (ulonglong2*)((char*)Ts + (size_t)(N0 + N1) * 16); // 3.2 MB
    float* S0 = (float*)d_out;

    hipMemsetAsync(S0, 0, (size_t)N0 * 512, stream);
    hipMemsetAsync(S1, 0, (size_t)N1 * 512, stream);
    hipMemsetAsync(S2, 0, (size_t)N2 * 512, stream);
    // NOTE: Ts memset deferred until bit buffers are dead.

    dim3 blk(256);
    k_bits_node<<<(N0 + 3) / 4, blk, 0, stream>>>(X0, Xb, N0);
    k_bits_edge<<<(N1 + 255) / 256, blk, 0, stream>>>(eidx, Xb, Eb, N1);
    k_bits_tri<<<(N2 + 255) / 256, blk, 0, stream>>>(tidx, Xb, Tb, N2);

    k_spmm_bin<<<(nnz0 + 3) / 4, blk, 0, stream>>>(L0r, L0c, L0v, Xb, S0, nnz0);
    k_spmm_bin<<<(nnz1 + 3) / 4, blk, 0, stream>>>(L1r, L1c, L1v, Eb, S1, nnz1);
    k_spmm_bin<<<(nnz2 + 3) / 4, blk, 0, stream>>>(L2r, L2c, L2v, Tb, S2, nnz2);

    // Bits now dead -> reclaim Ts.
    hipMemsetAsync(Ts, 0, (size_t)N1 * 512, stream);

    // H2 = prelu(S2 @ Wt^T + bt)   (in place)
    k_gemm<1, 0><<<(N2 + 31) / 32, blk, 0, stream>>>(S2, Wt, bt, nullptr, pw, S2, N2, 1.0f);
    // Ts = B2 @ H2
    k_spmm_dense<<<(nnzb2 + 3) / 4, blk, 0, stream>>>(B2r, B2c, B2v, S2, Ts, nnzb2, 1.0f);
    // H1 = prelu(S1 @ We^T + be)   (in place)
    k_gemm<1, 0><<<(N1 + 31) / 32, blk, 0, stream>>>(S1, We, be, nullptr, pw, S1, N1, 1.0f);
    // U = (Ts @ Wtri^T + btri) + H1   (in place over Ts)
    k_gemm<0, 1><<<(N1 + 31) / 32, blk, 0, stream>>>(Ts, Wtri, btri, S1, pw, Ts, N1, 1.0f);
    // d_out = prelu(S0 @ Wn^T + bn) / 3   (in place over d_out)
    k_gemm<1, 0><<<(N0 + 31) / 32, blk, 0, stream>>>(S0, Wn, bn, nullptr, pw, (float*)d_out, N0, 1.0f / 3.0f);
    // d_out += (1/3) * B1 @ U
    k_spmm_dense<<<(nnzb1 + 3) / 4, blk, 0, stream>>>(B1r, B1c, B1v, Ts, (float*)d_out, nnzb1, 1.0f / 3.0f);
}

// Round 7
// 1956.615 us; speedup vs baseline: 1.2594x; 1.2594x over previous
//
#include <hip/hip_runtime.h>
#include <hip/hip_bf16.h>
#include <stdint.h>

// ---------------------------------------------------------------------------
// PlanetoidSCN R7: binarize -> bitmask features -> binary SpMM (atomics) ->
// tiled GEMMs -> CSR-gather SpMM (no output atomics) -> fused combine.
//
// Workspace: S1 | S2 | Ts = 256,000,000 B exactly (known-safe from R6).
// Overlays (time-sliced, no new ws):
//   - Xb/Eb/Tb bit buffers in Ts head (dead once binary SpMMs done)
//   - B2 CSR (rp2/rf2/colp2/valp2/bsum2) in d_out (S0 pipeline moved last)
//   - Xb2 (recomputed) + B1 CSR in S2 region (dead after B2-gather)
// ---------------------------------------------------------------------------

__global__ __launch_bounds__(256) void k_bits_node(const float* __restrict__ X,
        ulonglong2* __restrict__ bits, int n)
{
    int wid = (blockIdx.x * 256 + threadIdx.x) >> 6;
    int lane = threadIdx.x & 63;
    if (wid >= n) return;
    const float* row = X + (size_t)wid * 128;
    unsigned long long m0 = __ballot(row[lane] != 0.0f);
    unsigned long long m1 = __ballot(row[lane + 64] != 0.0f);
    if (lane == 0) { bits[wid].x = m0; bits[wid].y = m1; }
}

__global__ __launch_bounds__(256) void k_bits_edge(const int* __restrict__ idx,
        const ulonglong2* __restrict__ nb, ulonglong2* __restrict__ outb, int n)
{
    int e = blockIdx.x * 256 + threadIdx.x;
    if (e >= n) return;
    ulonglong2 a = nb[idx[2 * e]];
    ulonglong2 b = nb[idx[2 * e + 1]];
    ulonglong2 r; r.x = a.x & b.x; r.y = a.y & b.y;
    outb[e] = r;
}

__global__ __launch_bounds__(256) void k_bits_tri(const int* __restrict__ idx,
        const ulonglong2* __restrict__ nb, ulonglong2* __restrict__ outb, int n)
{
    int e = blockIdx.x * 256 + threadIdx.x;
    if (e >= n) return;
    ulonglong2 a = nb[idx[3 * e]];
    ulonglong2 b = nb[idx[3 * e + 1]];
    ulonglong2 c = nb[idx[3 * e + 2]];
    ulonglong2 r; r.x = a.x & b.x & c.x; r.y = a.y & b.y & c.y;
    outb[e] = r;
}

// S[row] += val * bits(col): one wave per nnz, skip zero features.
__global__ __launch_bounds__(256) void k_spmm_bin(const int* __restrict__ rows,
        const int* __restrict__ cols, const float* __restrict__ vals,
        const ulonglong2* __restrict__ bits, float* __restrict__ S, int nnz)
{
    int nz = (blockIdx.x * 256 + threadIdx.x) >> 6;
    int lane = threadIdx.x & 63;
    if (nz >= nnz) return;
    int r = rows[nz], c = cols[nz];
    float v = vals[nz];
    ulonglong2 m = bits[c];
    float* out = S + (size_t)r * 128;
    if ((m.x >> lane) & 1ull) atomicAdd(out + lane, v);
    if ((m.y >> lane) & 1ull) atomicAdd(out + lane + 64, v);
}

// ---------------- CSR build: histogram -> scan -> scatter -------------------

__global__ __launch_bounds__(256) void k_hist(const int* __restrict__ rows,
        int* __restrict__ rp, int nnz)
{
    int nz = blockIdx.x * 256 + threadIdx.x;
    if (nz >= nnz) return;
    atomicAdd(&rp[rows[nz] + 1], 1);
}

// Inclusive scan, 1024 elems/block (256 thr x 4). Writes block total to bsum.
__global__ __launch_bounds__(256) void k_scan_block(int* __restrict__ a, int n,
        int* __restrict__ bsum)
{
    __shared__ int sm[256];
    int b = blockIdx.x, t = threadIdx.x;
    int g = b * 1024 + t * 4;
    int x0 = (g + 0 < n) ? a[g + 0] : 0;
    int x1 = (g + 1 < n) ? a[g + 1] : 0;
    int x2 = (g + 2 < n) ? a[g + 2] : 0;
    int x3 = (g + 3 < n) ? a[g + 3] : 0;
    int ts = x0 + x1 + x2 + x3;
    sm[t] = ts; __syncthreads();
    for (int ofs = 1; ofs < 256; ofs <<= 1) {
        int x = (t >= ofs) ? sm[t - ofs] : 0;
        __syncthreads();
        sm[t] += x;
        __syncthreads();
    }
    int excl = sm[t] - ts;
    if (g + 0 < n) a[g + 0] = excl + x0;
    if (g + 1 < n) a[g + 1] = excl + x0 + x1;
    if (g + 2 < n) a[g + 2] = excl + x0 + x1 + x2;
    if (g + 3 < n) a[g + 3] = excl + ts;
    if (t == 255) bsum[b] = sm[255];
}

// Single-block exclusive scan of <=256 block sums (in place).
__global__ __launch_bounds__(256) void k_scan_top(int* __restrict__ bsum, int nb)
{
    __shared__ int sm[256];
    int t = threadIdx.x;
    int v = (t < nb) ? bsum[t] : 0;
    sm[t] = v; __syncthreads();
    for (int ofs = 1; ofs < 256; ofs <<= 1) {
        int x = (t >= ofs) ? sm[t - ofs] : 0;
        __syncthreads();
        sm[t] += x;
        __syncthreads();
    }
    if (t < nb) bsum[t] = sm[t] - v;   // exclusive
}

__global__ __launch_bounds__(256) void k_scan_add(int* __restrict__ a, int n,
        const int* __restrict__ bsum)
{
    int g = blockIdx.x * 256 + threadIdx.x;
    if (g >= n) return;
    a[g] += bsum[g >> 10];
}

// perm-scatter: colp/valp in CSR order; rf is a consumable copy of rp.
__global__ __launch_bounds__(256) void k_scatter(const int* __restrict__ rows,
        const int* __restrict__ cols, const float* __restrict__ vals,
        int* __restrict__ rf, int* __restrict__ colp, float* __restrict__ valp,
        int nnz, float scale)
{
    int nz = blockIdx.x * 256 + threadIdx.x;
    if (nz >= nnz) return;
    int r = rows[nz];
    int pos = atomicAdd(&rf[r], 1);
    colp[pos] = cols[nz];
    valp[pos] = vals[nz] * scale;
}

// One wave per row: Out[r] = sum valp[i] * X[colp[i]]  (writes all rows).
__global__ __launch_bounds__(256) void k_gather_write(const int* __restrict__ rp,
        const int* __restrict__ colp, const float* __restrict__ valp,
        const float* __restrict__ X, float* __restrict__ Out, int nrows)
{
    int r = (blockIdx.x * 256 + threadIdx.x) >> 6;
    int lane = threadIdx.x & 63;
    if (r >= nrows) return;
    int s = rp[r], e = rp[r + 1];
    float2 acc = make_float2(0.f, 0.f);
    for (int i = s; i < e; ++i) {
        int c = colp[i];
        float v = valp[i];
        float2 x = *(const float2*)(X + (size_t)c * 128 + lane * 2);
        acc.x += v * x.x;
        acc.y += v * x.y;
    }
    *(float2*)(Out + (size_t)r * 128 + lane * 2) = acc;
}

// One wave per row: Out[r] += sum valp[i] * X[colp[i]]  (skip empty rows).
__global__ __launch_bounds__(256) void k_gather_add(const int* __restrict__ rp,
        const int* __restrict__ colp, const float* __restrict__ valp,
        const float* __restrict__ X, float* __restrict__ Out, int nrows)
{
    int r = (blockIdx.x * 256 + threadIdx.x) >> 6;
    int lane = threadIdx.x & 63;
    if (r >= nrows) return;
    int s = rp[r], e = rp[r + 1];
    if (s == e) return;
    float2 acc = make_float2(0.f, 0.f);
    for (int i = s; i < e; ++i) {
        int c = colp[i];
        float v = valp[i];
        float2 x = *(const float2*)(X + (size_t)c * 128 + lane * 2);
        acc.x += v * x.x;
        acc.y += v * x.y;
    }
    float* o = Out + (size_t)r * 128 + lane * 2;
    float2 cur = *(float2*)o;
    cur.x += acc.x; cur.y += acc.y;
    *(float2*)o = cur;
}

// H[r] = (prelu?)(S[r] @ W^T + b) * scale (+ addsrc[r]); W row-major [128][128].
// In-place safe: each block stages its own 32 rows to LDS before overwriting.
template<int PRELU, int ADDSRC>
__global__ __launch_bounds__(256) void k_gemm(const float* __restrict__ S,
        const float* __restrict__ W, const float* __restrict__ bias,
        const float* __restrict__ addsrc, const float* __restrict__ pw,
        float* __restrict__ H, int n_rows, float scale)
{
    __shared__ float Sl[32][128];   // 16 KB
    const int t = threadIdx.x;
    const int ot = t & 31, rt = t >> 5;
    const int o0 = ot * 4;
    const int row_base = blockIdx.x * 32;

    for (int i = t; i < 32 * 32; i += 256) {   // 32 rows x 32 float4
        int r = i >> 5, c = i & 31;
        int gr = row_base + r;
        float4 v = make_float4(0.f, 0.f, 0.f, 0.f);
        if (gr < n_rows) v = *(const float4*)(S + (size_t)gr * 128 + c * 4);
        *(float4*)(&Sl[r][c * 4]) = v;
    }
    __syncthreads();

    float acc[4][4];
#pragma unroll
    for (int j = 0; j < 4; ++j)
#pragma unroll
        for (int k = 0; k < 4; ++k) acc[j][k] = 0.f;

    for (int f0 = 0; f0 < 128; f0 += 4) {
        float4 wv[4], sv[4];
#pragma unroll
        for (int k = 0; k < 4; ++k)
            wv[k] = *(const float4*)(W + (size_t)(o0 + k) * 128 + f0);
#pragma unroll
        for (int j = 0; j < 4; ++j)
            sv[j] = *(const float4*)(&Sl[rt * 4 + j][f0]);
#pragma unroll
        for (int j = 0; j < 4; ++j)
#pragma unroll
            for (int k = 0; k < 4; ++k)
                acc[j][k] += sv[j].x * wv[k].x + sv[j].y * wv[k].y
                           + sv[j].z * wv[k].z + sv[j].w * wv[k].w;
    }

    float4 bv = *(const float4*)(bias + o0);
    float w = 0.0f;
    if (PRELU) w = pw[0];
#pragma unroll
    for (int j = 0; j < 4; ++j) {
        int gr = row_base + rt * 4 + j;
        if (gr >= n_rows) continue;
        float4 x;
        x.x = acc[j][0] + bv.x; x.y = acc[j][1] + bv.y;
        x.z = acc[j][2] + bv.z; x.w = acc[j][3] + bv.w;
        if (PRELU) {
            x.x = x.x >= 0.f ? x.x : w * x.x;
            x.y = x.y >= 0.f ? x.y : w * x.y;
            x.z = x.z >= 0.f ? x.z : w * x.z;
            x.w = x.w >= 0.f ? x.w : w * x.w;
        }
        x.x *= scale; x.y *= scale; x.z *= scale; x.w *= scale;
        if (ADDSRC) {
            const float4 a = *(const float4*)(addsrc + (size_t)gr * 128 + o0);
            x.x += a.x; x.y += a.y; x.z += a.z; x.w += a.w;
        }
        *(float4*)(H + (size_t)gr * 128 + o0) = x;
    }
}

extern "C" void kernel_launch(void* const* d_in, const int* in_sizes, int n_in,
                              void* d_out, int out_size, void* d_ws, size_t ws_size,
                              hipStream_t stream)
{
    const float* X0  = (const float*)d_in[0];
    const int*  eidx = (const int*)  d_in[1];
    const int*  tidx = (const int*)  d_in[2];
    const int* L0r = (const int*)d_in[3];
    const int* L0c = (const int*)d_in[4];
    const float* L0v = (const float*)d_in[5];
    const int* L1r = (const int*)d_in[6];
    const int* L1c = (const int*)d_in[7];
    const float* L1v = (const float*)d_in[8];
    const int* L2r = (const int*)d_in[9];
    const int* L2c = (const int*)d_in[10];
    const float* L2v = (const float*)d_in[11];
    const int* B1r = (const int*)d_in[12];
    const int* B1c = (const int*)d_in[13];
    const float* B1v = (const float*)d_in[14];
    const int* B2r = (const int*)d_in[15];
    const int* B2c = (const int*)d_in[16];
    const float* B2v = (const float*)d_in[17];
    const float* Wn   = (const float*)d_in[18];
    const float* bn   = (const float*)d_in[19];
    const float* We   = (const float*)d_in[20];
    const float* be   = (const float*)d_in[21];
    const float* Wt   = (const float*)d_in[22];
    const float* bt   = (const float*)d_in[23];
    const float* Wtri = (const float*)d_in[24];
    const float* btri = (const float*)d_in[25];
    const float* pw   = (const float*)d_in[26];

    const int N0 = in_sizes[0] / 128;
    const int N1 = in_sizes[1] / 2;
    const int N2 = in_sizes[2] / 3;
    const int nnz0 = in_sizes[3], nnz1 = in_sizes[6], nnz2 = in_sizes[9];
    const int nnzb1 = in_sizes[12], nnzb2 = in_sizes[15];

    // --- base workspace: S1 | S2 | Ts = 256,000,000 B exactly ---
    char* ws = (char*)d_ws;
    size_t off = 0;
    auto take = [&](size_t bytes) {
        void* p = ws + off;
        off += (bytes + 255) & ~(size_t)255;
        return p;
    };
    float* S1 = (float*)take((size_t)N1 * 512);
    float* S2 = (float*)take((size_t)N2 * 512);
    float* Ts = (float*)take((size_t)N1 * 512);

    // bit buffers overlay Ts head (dead before Ts first written)
    ulonglong2* Xb = (ulonglong2*)Ts;
    ulonglong2* Eb = (ulonglong2*)((char*)Ts + (size_t)N0 * 16);
    ulonglong2* Tb = (ulonglong2*)((char*)Ts + (size_t)(N0 + N1) * 16);

    // B2 CSR overlays d_out (S0 pipeline runs last)
    auto align256 = [](size_t x) { return (x + 255) & ~(size_t)255; };
    char* dob = (char*)d_out;
    size_t doff = 0;
    int*   rp2   = (int*)(dob + doff); doff += align256((size_t)(N1 + 1) * 4);
    int*   rf2   = (int*)(dob + doff); doff += align256((size_t)(N1 + 1) * 4);
    int*   colp2 = (int*)(dob + doff); doff += align256((size_t)nnzb2 * 4);
    float* valp2 = (float*)(dob + doff); doff += align256((size_t)nnzb2 * 4);
    int*   bsum2 = (int*)(dob + doff); doff += 1024;

    // B1 CSR + recomputed node bits overlay S2 (dead after B2-gather)
    char* s2b = (char*)S2;
    size_t soff = 0;
    ulonglong2* Xb2 = (ulonglong2*)(s2b + soff); soff += align256((size_t)N0 * 16);
    int*   rp1   = (int*)(s2b + soff); soff += align256((size_t)(N0 + 1) * 4);
    int*   rf1   = (int*)(s2b + soff); soff += align256((size_t)(N0 + 1) * 4);
    int*   colp1 = (int*)(s2b + soff); soff += align256((size_t)nnzb1 * 4);
    float* valp1 = (float*)(s2b + soff); soff += align256((size_t)nnzb1 * 4);
    int*   bsum1 = (int*)(s2b + soff); soff += 1024;

    dim3 blk(256);

    // --- phase A: bits + binary SpMMs into S1/S2 ---
    hipMemsetAsync(S1, 0, (size_t)N1 * 512, stream);
    hipMemsetAsync(S2, 0, (size_t)N2 * 512, stream);
    k_bits_node<<<(N0 + 3) / 4, blk, 0, stream>>>(X0, Xb, N0);
    k_bits_edge<<<(N1 + 255) / 256, blk, 0, stream>>>(eidx, Xb, Eb, N1);
    k_bits_tri<<<(N2 + 255) / 256, blk, 0, stream>>>(tidx, Xb, Tb, N2);
    k_spmm_bin<<<(nnz1 + 3) / 4, blk, 0, stream>>>(L1r, L1c, L1v, Eb, S1, nnz1);
    k_spmm_bin<<<(nnz2 + 3) / 4, blk, 0, stream>>>(L2r, L2c, L2v, Tb, S2, nnz2);

    // --- B2 CSR build (in d_out region) ---
    {
        int n = N1 + 1;
        int nb = (n + 1023) / 1024;
        hipMemsetAsync(rp2, 0, (size_t)n * 4, stream);
        k_hist<<<(nnzb2 + 255) / 256, blk, 0, stream>>>(B2r, rp2, nnzb2);
        k_scan_block<<<nb, blk, 0, stream>>>(rp2, n, bsum2);
        k_scan_top<<<1, blk, 0, stream>>>(bsum2, nb);
        k_scan_add<<<(n + 255) / 256, blk, 0, stream>>>(rp2, n, bsum2);
        hipMemcpyAsync(rf2, rp2, (size_t)n * 4, hipMemcpyDeviceToDevice, stream);
        k_scatter<<<(nnzb2 + 255) / 256, blk, 0, stream>>>(B2r, B2c, B2v, rf2,
                colp2, valp2, nnzb2, 1.0f);
    }

    // --- H2 = prelu(S2 @ Wt^T + bt) (in place) ---
    k_gemm<1, 0><<<(N2 + 31) / 32, blk, 0, stream>>>(S2, Wt, bt, nullptr, pw, S2, N2, 1.0f);
    // --- Ts = B2 @ H2 (gather; writes every row, clobbers bit overlay) ---
    k_gather_write<<<(N1 + 3) / 4, blk, 0, stream>>>(rp2, colp2, valp2, S2, Ts, N1);
    // --- H1 = prelu(S1 @ We^T + be) (in place) ---
    k_gemm<1, 0><<<(N1 + 31) / 32, blk, 0, stream>>>(S1, We, be, nullptr, pw, S1, N1, 1.0f);
    // --- U = (Ts @ Wtri^T + btri) + H1 (in place over Ts; S1 dies after) ---
    k_gemm<0, 1><<<(N1 + 31) / 32, blk, 0, stream>>>(Ts, Wtri, btri, S1, pw, Ts, N1, 1.0f);

    // --- phase B: S2 region now free -> node bits again + B1 CSR ---
    k_bits_node<<<(N0 + 3) / 4, blk, 0, stream>>>(X0, Xb2, N0);
    {
        int n = N0 + 1;
        int nb = (n + 1023) / 1024;
        hipMemsetAsync(rp1, 0, (size_t)n * 4, stream);
        k_hist<<<(nnzb1 + 255) / 256, blk, 0, stream>>>(B1r, rp1, nnzb1);
        k_scan_block<<<nb, blk, 0, stream>>>(rp1, n, bsum1);
        k_scan_top<<<1, blk, 0, stream>>>(bsum1, nb);
        k_scan_add<<<(n + 255) / 256, blk, 0, stream>>>(rp1, n, bsum1);
        hipMemcpyAsync(rf1, rp1, (size_t)n * 4, hipMemcpyDeviceToDevice, stream);
        k_scatter<<<(nnzb1 + 255) / 256, blk, 0, stream>>>(B1r, B1c, B1v, rf1,
                colp1, valp1, nnzb1, 1.0f / 3.0f);
    }

    // --- S0 pipeline (d_out region now free of B2 CSR) ---
    hipMemsetAsync(d_out, 0, (size_t)N0 * 512, stream);
    k_spmm_bin<<<(nnz0 + 3) / 4, blk, 0, stream>>>(L0r, L0c, L0v, Xb2, (float*)d_out, nnz0);
    // d_out = prelu(S0 @ Wn^T + bn) / 3   (in place)
    k_gemm<1, 0><<<(N0 + 31) / 32, blk, 0, stream>>>((float*)d_out, Wn, bn, nullptr, pw,
            (float*)d_out, N0, 1.0f / 3.0f);
    // d_out += B1 @ U (valp1 pre-scaled by 1/3; non-atomic, one wave per row)
    k_gather_add<<<(N0 + 3) / 4, blk, 0, stream>>>(rp1, colp1, valp1, Ts, (float*)d_out, N0);
}

// Round 8
// 1167.492 us; speedup vs baseline: 2.1107x; 1.6759x over previous
//
#include <hip/hip_runtime.h>
#include <hip/hip_bf16.h>
#include <stdint.h>

// ---------------------------------------------------------------------------
// PlanetoidSCN R8: binarize -> bitmask features -> binary SpMM (atomics) ->
// split-bf16 MFMA GEMMs -> CSR-gather SpMM (no output atomics) -> combine.
//
// Workspace: S1 | S2 | Ts = 256,000,000 B exactly (known-safe from R6).
// Overlays (time-sliced, no new ws):
//   - Xb/Eb/Tb bit buffers in Ts head (dead once binary SpMMs done)
//   - B2 CSR + Wt/We/Wtri bf16 splits in d_out (S0 pipeline runs last)
//   - Xb2 + B1 CSR + Wn bf16 split in S2 region (dead after B2-gather)
// ---------------------------------------------------------------------------

typedef __attribute__((ext_vector_type(8))) short bf16x8;
typedef __attribute__((ext_vector_type(4))) float f32x4;

__device__ __forceinline__ short f2bf(float x) {
    __hip_bfloat16 h = __float2bfloat16(x);
    return *reinterpret_cast<short*>(&h);
}
__device__ __forceinline__ float bf2f(short s) {
    __hip_bfloat16 h = *reinterpret_cast<__hip_bfloat16*>(&s);
    return __bfloat162float(h);
}

__global__ __launch_bounds__(256) void k_bits_node(const float* __restrict__ X,
        ulonglong2* __restrict__ bits, int n)
{
    int wid = (blockIdx.x * 256 + threadIdx.x) >> 6;
    int lane = threadIdx.x & 63;
    if (wid >= n) return;
    const float* row = X + (size_t)wid * 128;
    unsigned long long m0 = __ballot(row[lane] != 0.0f);
    unsigned long long m1 = __ballot(row[lane + 64] != 0.0f);
    if (lane == 0) { bits[wid].x = m0; bits[wid].y = m1; }
}

__global__ __launch_bounds__(256) void k_bits_edge(const int* __restrict__ idx,
        const ulonglong2* __restrict__ nb, ulonglong2* __restrict__ outb, int n)
{
    int e = blockIdx.x * 256 + threadIdx.x;
    if (e >= n) return;
    ulonglong2 a = nb[idx[2 * e]];
    ulonglong2 b = nb[idx[2 * e + 1]];
    ulonglong2 r; r.x = a.x & b.x; r.y = a.y & b.y;
    outb[e] = r;
}

__global__ __launch_bounds__(256) void k_bits_tri(const int* __restrict__ idx,
        const ulonglong2* __restrict__ nb, ulonglong2* __restrict__ outb, int n)
{
    int e = blockIdx.x * 256 + threadIdx.x;
    if (e >= n) return;
    ulonglong2 a = nb[idx[3 * e]];
    ulonglong2 b = nb[idx[3 * e + 1]];
    ulonglong2 c = nb[idx[3 * e + 2]];
    ulonglong2 r; r.x = a.x & b.x & c.x; r.y = a.y & b.y & c.y;
    outb[e] = r;
}

// S[row] += val * bits(col): one wave per nnz, skip zero features.
__global__ __launch_bounds__(256) void k_spmm_bin(const int* __restrict__ rows,
        const int* __restrict__ cols, const float* __restrict__ vals,
        const ulonglong2* __restrict__ bits, float* __restrict__ S, int nnz)
{
    int nz = (blockIdx.x * 256 + threadIdx.x) >> 6;
    int lane = threadIdx.x & 63;
    if (nz >= nnz) return;
    int r = rows[nz], c = cols[nz];
    float v = vals[nz];
    ulonglong2 m = bits[c];
    float* out = S + (size_t)r * 128;
    if ((m.x >> lane) & 1ull) atomicAdd(out + lane, v);
    if ((m.y >> lane) & 1ull) atomicAdd(out + lane + 64, v);
}

// ---------------- CSR build: histogram -> scan -> scatter -------------------

__global__ __launch_bounds__(256) void k_hist(const int* __restrict__ rows,
        int* __restrict__ rp, int nnz)
{
    int nz = blockIdx.x * 256 + threadIdx.x;
    if (nz >= nnz) return;
    atomicAdd(&rp[rows[nz] + 1], 1);
}

__global__ __launch_bounds__(256) void k_scan_block(int* __restrict__ a, int n,
        int* __restrict__ bsum)
{
    __shared__ int sm[256];
    int b = blockIdx.x, t = threadIdx.x;
    int g = b * 1024 + t * 4;
    int x0 = (g + 0 < n) ? a[g + 0] : 0;
    int x1 = (g + 1 < n) ? a[g + 1] : 0;
    int x2 = (g + 2 < n) ? a[g + 2] : 0;
    int x3 = (g + 3 < n) ? a[g + 3] : 0;
    int ts = x0 + x1 + x2 + x3;
    sm[t] = ts; __syncthreads();
    for (int ofs = 1; ofs < 256; ofs <<= 1) {
        int x = (t >= ofs) ? sm[t - ofs] : 0;
        __syncthreads();
        sm[t] += x;
        __syncthreads();
    }
    int excl = sm[t] - ts;
    if (g + 0 < n) a[g + 0] = excl + x0;
    if (g + 1 < n) a[g + 1] = excl + x0 + x1;
    if (g + 2 < n) a[g + 2] = excl + x0 + x1 + x2;
    if (g + 3 < n) a[g + 3] = excl + ts;
    if (t == 255) bsum[b] = sm[255];
}

__global__ __launch_bounds__(256) void k_scan_top(int* __restrict__ bsum, int nb)
{
    __shared__ int sm[256];
    int t = threadIdx.x;
    int v = (t < nb) ? bsum[t] : 0;
    sm[t] = v; __syncthreads();
    for (int ofs = 1; ofs < 256; ofs <<= 1) {
        int x = (t >= ofs) ? sm[t - ofs] : 0;
        __syncthreads();
        sm[t] += x;
        __syncthreads();
    }
    if (t < nb) bsum[t] = sm[t] - v;   // exclusive
}

__global__ __launch_bounds__(256) void k_scan_add(int* __restrict__ a, int n,
        const int* __restrict__ bsum)
{
    int g = blockIdx.x * 256 + threadIdx.x;
    if (g >= n) return;
    a[g] += bsum[g >> 10];
}

__global__ __launch_bounds__(256) void k_scatter(const int* __restrict__ rows,
        const int* __restrict__ cols, const float* __restrict__ vals,
        int* __restrict__ rf, int* __restrict__ colp, float* __restrict__ valp,
        int nnz, float scale)
{
    int nz = blockIdx.x * 256 + threadIdx.x;
    if (nz >= nnz) return;
    int r = rows[nz];
    int pos = atomicAdd(&rf[r], 1);
    colp[pos] = cols[nz];
    valp[pos] = vals[nz] * scale;
}

// One wave per row: Out[r] = sum valp[i] * X[colp[i]]  (writes all rows).
__global__ __launch_bounds__(256) void k_gather_write(const int* __restrict__ rp,
        const int* __restrict__ colp, const float* __restrict__ valp,
        const float* __restrict__ X, float* __restrict__ Out, int nrows)
{
    int r = (blockIdx.x * 256 + threadIdx.x) >> 6;
    int lane = threadIdx.x & 63;
    if (r >= nrows) return;
    int s = rp[r], e = rp[r + 1];
    float2 acc = make_float2(0.f, 0.f);
    for (int i = s; i < e; ++i) {
        int c = colp[i];
        float v = valp[i];
        float2 x = *(const float2*)(X + (size_t)c * 128 + lane * 2);
        acc.x += v * x.x;
        acc.y += v * x.y;
    }
    *(float2*)(Out + (size_t)r * 128 + lane * 2) = acc;
}

// One wave per row: Out[r] += sum valp[i] * X[colp[i]]  (skip empty rows).
__global__ __launch_bounds__(256) void k_gather_add(const int* __restrict__ rp,
        const int* __restrict__ colp, const float* __restrict__ valp,
        const float* __restrict__ X, float* __restrict__ Out, int nrows)
{
    int r = (blockIdx.x * 256 + threadIdx.x) >> 6;
    int lane = threadIdx.x & 63;
    if (r >= nrows) return;
    int s = rp[r], e = rp[r + 1];
    if (s == e) return;
    float2 acc = make_float2(0.f, 0.f);
    for (int i = s; i < e; ++i) {
        int c = colp[i];
        float v = valp[i];
        float2 x = *(const float2*)(X + (size_t)c * 128 + lane * 2);
        acc.x += v * x.x;
        acc.y += v * x.y;
    }
    float* o = Out + (size_t)r * 128 + lane * 2;
    float2 cur = *(float2*)o;
    cur.x += acc.x; cur.y += acc.y;
    *(float2*)o = cur;
}

// Split f32 W -> bf16 hi + bf16 lo (RNE both stages).
__global__ __launch_bounds__(256) void k_wsplit(const float* __restrict__ W,
        short* __restrict__ hi, short* __restrict__ lo, int n)
{
    int i = blockIdx.x * 256 + threadIdx.x;
    if (i >= n) return;
    float x = W[i];
    short h = f2bf(x);
    hi[i] = h;
    lo[i] = f2bf(x - bf2f(h));
}

// ---------------------------------------------------------------------------
// Split-bf16 MFMA GEMM: H = epi(S @ W^T + b). W given pre-split (hi/lo bf16,
// row-major [128][128]). Block = 256 thr = 4 waves; tile = 64 rows x 128 cols.
// Wave w owns rows [base+16w, base+16w+16): 8 col-tiles x 4 k-steps x 3 MFMA.
// C ~= Shi*Whi + Shi*Wlo + Slo*Whi (f32 accum); |err| <~ 128*2^-18*|S||W|.
// LDS W staged at stride 136 (2-way bank alias only). In-place safe: each
// row's S is read only by its owning wave, before that wave's epilogue.
// ---------------------------------------------------------------------------
template<int PRELU, int ADDSRC>
__global__ __launch_bounds__(256) void k_gemm_mfma(const float* __restrict__ S,
        const short* __restrict__ Whi, const short* __restrict__ Wlo,
        const float* __restrict__ bias, const float* __restrict__ addsrc,
        const float* __restrict__ pw, float* __restrict__ H, int n_rows,
        float scale)
{
    __shared__ short Wh[128 * 136];
    __shared__ short Wl[128 * 136];
    const int t = threadIdx.x;

    const uint32_t* gh = (const uint32_t*)Whi;
    const uint32_t* gl = (const uint32_t*)Wlo;
    for (int i = t; i < 128 * 64; i += 256) {      // u32 = 2 bf16
        int r = i >> 6, cp = i & 63;
        *(uint32_t*)&Wh[r * 136 + cp * 2] = gh[r * 64 + cp];
        *(uint32_t*)&Wl[r * 136 + cp * 2] = gl[r * 64 + cp];
    }
    __syncthreads();

    const int wave = t >> 6, lane = t & 63;
    const int lm = lane & 15, kg = lane >> 4;
    const int band = blockIdx.x * 64 + wave * 16;
    const int row_a = band + lm;                   // A-operand row for this lane
    const bool arow_ok = row_a < n_rows;

    f32x4 acc[8];
#pragma unroll
    for (int ct = 0; ct < 8; ++ct) acc[ct] = (f32x4){0.f, 0.f, 0.f, 0.f};

    for (int ks = 0; ks < 4; ++ks) {
        const int k0 = ks * 32 + kg * 8;
        float a[8];
        if (arow_ok) {
            float4 v0 = *(const float4*)(S + (size_t)row_a * 128 + k0);
            float4 v1 = *(const float4*)(S + (size_t)row_a * 128 + k0 + 4);
            a[0]=v0.x; a[1]=v0.y; a[2]=v0.z; a[3]=v0.w;
            a[4]=v1.x; a[5]=v1.y; a[6]=v1.z; a[7]=v1.w;
        } else {
#pragma unroll
            for (int i = 0; i < 8; ++i) a[i] = 0.f;
        }
        bf16x8 ahi, alo;
#pragma unroll
        for (int i = 0; i < 8; ++i) {
            short h = f2bf(a[i]);
            ahi[i] = h;
            alo[i] = f2bf(a[i] - bf2f(h));
        }
#pragma unroll
        for (int ct = 0; ct < 8; ++ct) {
            const int brow = ct * 16 + lm;
            bf16x8 bhi = *(const bf16x8*)&Wh[brow * 136 + k0];
            bf16x8 blo = *(const bf16x8*)&Wl[brow * 136 + k0];
            acc[ct] = __builtin_amdgcn_mfma_f32_16x16x32_bf16(ahi, bhi, acc[ct], 0, 0, 0);
            acc[ct] = __builtin_amdgcn_mfma_f32_16x16x32_bf16(ahi, blo, acc[ct], 0, 0, 0);
            acc[ct] = __builtin_amdgcn_mfma_f32_16x16x32_bf16(alo, bhi, acc[ct], 0, 0, 0);
        }
    }

    // C/D: col = ct*16 + (lane&15), row = band + (lane>>4)*4 + j
    const int r0 = band + kg * 4;
    float w = 0.f;
    if (PRELU) w = pw[0];
#pragma unroll
    for (int ct = 0; ct < 8; ++ct) {
        const int col = ct * 16 + lm;
        const float b = bias[col];
#pragma unroll
        for (int j = 0; j < 4; ++j) {
            const int row = r0 + j;
            if (row >= n_rows) continue;
            float x = acc[ct][j] + b;
            if (PRELU) x = x >= 0.f ? x : w * x;
            x *= scale;
            if (ADDSRC) x += addsrc[(size_t)row * 128 + col];
            H[(size_t)row * 128 + col] = x;
        }
    }
}

extern "C" void kernel_launch(void* const* d_in, const int* in_sizes, int n_in,
                              void* d_out, int out_size, void* d_ws, size_t ws_size,
                              hipStream_t stream)
{
    const float* X0  = (const float*)d_in[0];
    const int*  eidx = (const int*)  d_in[1];
    const int*  tidx = (const int*)  d_in[2];
    const int* L0r = (const int*)d_in[3];
    const int* L0c = (const int*)d_in[4];
    const float* L0v = (const float*)d_in[5];
    const int* L1r = (const int*)d_in[6];
    const int* L1c = (const int*)d_in[7];
    const float* L1v = (const float*)d_in[8];
    const int* L2r = (const int*)d_in[9];
    const int* L2c = (const int*)d_in[10];
    const float* L2v = (const float*)d_in[11];
    const int* B1r = (const int*)d_in[12];
    const int* B1c = (const int*)d_in[13];
    const float* B1v = (const float*)d_in[14];
    const int* B2r = (const int*)d_in[15];
    const int* B2c = (const int*)d_in[16];
    const float* B2v = (const float*)d_in[17];
    const float* Wn   = (const float*)d_in[18];
    const float* bn   = (const float*)d_in[19];
    const float* We   = (const float*)d_in[20];
    const float* be   = (const float*)d_in[21];
    const float* Wt   = (const float*)d_in[22];
    const float* bt   = (const float*)d_in[23];
    const float* Wtri = (const float*)d_in[24];
    const float* btri = (const float*)d_in[25];
    const float* pw   = (const float*)d_in[26];

    const int N0 = in_sizes[0] / 128;
    const int N1 = in_sizes[1] / 2;
    const int N2 = in_sizes[2] / 3;
    const int nnz0 = in_sizes[3], nnz1 = in_sizes[6], nnz2 = in_sizes[9];
    const int nnzb1 = in_sizes[12], nnzb2 = in_sizes[15];

    // --- base workspace: S1 | S2 | Ts = 256,000,000 B exactly ---
    char* ws = (char*)d_ws;
    size_t off = 0;
    auto take = [&](size_t bytes) {
        void* p = ws + off;
        off += (bytes + 255) & ~(size_t)255;
        return p;
    };
    float* S1 = (float*)take((size_t)N1 * 512);
    float* S2 = (float*)take((size_t)N2 * 512);
    float* Ts = (float*)take((size_t)N1 * 512);

    // bit buffers overlay Ts head (dead before Ts first written)
    ulonglong2* Xb = (ulonglong2*)Ts;
    ulonglong2* Eb = (ulonglong2*)((char*)Ts + (size_t)N0 * 16);
    ulonglong2* Tb = (ulonglong2*)((char*)Ts + (size_t)(N0 + N1) * 16);

    // B2 CSR + Wt/We/Wtri splits overlay d_out (S0 pipeline runs last)
    auto align256 = [](size_t x) { return (x + 255) & ~(size_t)255; };
    char* dob = (char*)d_out;
    size_t doff = 0;
    int*   rp2   = (int*)(dob + doff); doff += align256((size_t)(N1 + 1) * 4);
    int*   rf2   = (int*)(dob + doff); doff += align256((size_t)(N1 + 1) * 4);
    int*   colp2 = (int*)(dob + doff); doff += align256((size_t)nnzb2 * 4);
    float* valp2 = (float*)(dob + doff); doff += align256((size_t)nnzb2 * 4);
    int*   bsum2 = (int*)(dob + doff); doff += 1024;
    short* WThi  = (short*)(dob + doff); doff += 32768;   // 128*128*2 B each
    short* WTlo  = (short*)(dob + doff); doff += 32768;
    short* WEhi  = (short*)(dob + doff); doff += 32768;
    short* WElo  = (short*)(dob + doff); doff += 32768;
    short* WRhi  = (short*)(dob + doff); doff += 32768;
    short* WRlo  = (short*)(dob + doff); doff += 32768;

    // B1 CSR + node bits + Wn split overlay S2 (dead after B2-gather)
    char* s2b = (char*)S2;
    size_t soff = 0;
    ulonglong2* Xb2 = (ulonglong2*)(s2b + soff); soff += align256((size_t)N0 * 16);
    int*   rp1   = (int*)(s2b + soff); soff += align256((size_t)(N0 + 1) * 4);
    int*   rf1   = (int*)(s2b + soff); soff += align256((size_t)(N0 + 1) * 4);
    int*   colp1 = (int*)(s2b + soff); soff += align256((size_t)nnzb1 * 4);
    float* valp1 = (float*)(s2b + soff); soff += align256((size_t)nnzb1 * 4);
    int*   bsum1 = (int*)(s2b + soff); soff += 1024;
    short* WNhi  = (short*)(s2b + soff); soff += 32768;
    short* WNlo  = (short*)(s2b + soff); soff += 32768;

    dim3 blk(256);

    // --- phase A: bits + binary SpMMs into S1/S2 ---
    hipMemsetAsync(S1, 0, (size_t)N1 * 512, stream);
    hipMemsetAsync(S2, 0, (size_t)N2 * 512, stream);
    k_bits_node<<<(N0 + 3) / 4, blk, 0, stream>>>(X0, Xb, N0);
    k_bits_edge<<<(N1 + 255) / 256, blk, 0, stream>>>(eidx, Xb, Eb, N1);
    k_bits_tri<<<(N2 + 255) / 256, blk, 0, stream>>>(tidx, Xb, Tb, N2);
    k_spmm_bin<<<(nnz1 + 3) / 4, blk, 0, stream>>>(L1r, L1c, L1v, Eb, S1, nnz1);
    k_spmm_bin<<<(nnz2 + 3) / 4, blk, 0, stream>>>(L2r, L2c, L2v, Tb, S2, nnz2);

    // --- weight splits (d_out overlay) ---
    k_wsplit<<<64, blk, 0, stream>>>(Wt,   WThi, WTlo, 16384);
    k_wsplit<<<64, blk, 0, stream>>>(We,   WEhi, WElo, 16384);
    k_wsplit<<<64, blk, 0, stream>>>(Wtri, WRhi, WRlo, 16384);

    // --- B2 CSR build (d_out overlay) ---
    {
        int n = N1 + 1;
        int nb = (n + 1023) / 1024;
        hipMemsetAsync(rp2, 0, (size_t)n * 4, stream);
        k_hist<<<(nnzb2 + 255) / 256, blk, 0, stream>>>(B2r, rp2, nnzb2);
        k_scan_block<<<nb, blk, 0, stream>>>(rp2, n, bsum2);
        k_scan_top<<<1, blk, 0, stream>>>(bsum2, nb);
        k_scan_add<<<(n + 255) / 256, blk, 0, stream>>>(rp2, n, bsum2);
        hipMemcpyAsync(rf2, rp2, (size_t)n * 4, hipMemcpyDeviceToDevice, stream);
        k_scatter<<<(nnzb2 + 255) / 256, blk, 0, stream>>>(B2r, B2c, B2v, rf2,
                colp2, valp2, nnzb2, 1.0f);
    }

    // --- H2 = prelu(S2 @ Wt^T + bt) (in place, MFMA) ---
    k_gemm_mfma<1, 0><<<(N2 + 63) / 64, blk, 0, stream>>>(S2, WThi, WTlo, bt,
            nullptr, pw, S2, N2, 1.0f);
    // --- H1 = prelu(S1 @ We^T + be) (in place, MFMA; before Ts clobber) ---
    k_gemm_mfma<1, 0><<<(N1 + 63) / 64, blk, 0, stream>>>(S1, WEhi, WElo, be,
            nullptr, pw, S1, N1, 1.0f);
    // --- Ts = B2 @ H2 (gather; writes every row, clobbers bit overlay) ---
    k_gather_write<<<(N1 + 3) / 4, blk, 0, stream>>>(rp2, colp2, valp2, S2, Ts, N1);
    // --- U = (Ts @ Wtri^T + btri) + H1 (in place over Ts; S1 dies after) ---
    k_gemm_mfma<0, 1><<<(N1 + 63) / 64, blk, 0, stream>>>(Ts, WRhi, WRlo, btri,
            S1, pw, Ts, N1, 1.0f);

    // --- phase B: S2 region now free -> node bits + B1 CSR + Wn split ---
    k_bits_node<<<(N0 + 3) / 4, blk, 0, stream>>>(X0, Xb2, N0);
    k_wsplit<<<64, blk, 0, stream>>>(Wn, WNhi, WNlo, 16384);
    {
        int n = N0 + 1;
        int nb = (n + 1023) / 1024;
        hipMemsetAsync(rp1, 0, (size_t)n * 4, stream);
        k_hist<<<(nnzb1 + 255) / 256, blk, 0, stream>>>(B1r, rp1, nnzb1);
        k_scan_block<<<nb, blk, 0, stream>>>(rp1, n, bsum1);
        k_scan_top<<<1, blk, 0, stream>>>(bsum1, nb);
        k_scan_add<<<(n + 255) / 256, blk, 0, stream>>>(rp1, n, bsum1);
        hipMemcpyAsync(rf1, rp1, (size_t)n * 4, hipMemcpyDeviceToDevice, stream);
        k_scatter<<<(nnzb1 + 255) / 256, blk, 0, stream>>>(B1r, B1c, B1v, rf1,
                colp1, valp1, nnzb1, 1.0f / 3.0f);
    }

    // --- S0 pipeline (d_out region now free of B2 CSR + W splits) ---
    hipMemsetAsync(d_out, 0, (size_t)N0 * 512, stream);
    k_spmm_bin<<<(nnz0 + 3) / 4, blk, 0, stream>>>(L0r, L0c, L0v, Xb2, (float*)d_out, nnz0);
    // d_out = prelu(S0 @ Wn^T + bn) / 3   (in place, MFMA)
    k_gemm_mfma<1, 0><<<(N0 + 63) / 64, blk, 0, stream>>>((float*)d_out, WNhi, WNlo,
            bn, nullptr, pw, (float*)d_out, N0, 1.0f / 3.0f);
    // d_out += B1 @ U (valp1 pre-scaled by 1/3; non-atomic, one wave per row)
    k_gather_add<<<(N0 + 3) / 4, blk, 0, stream>>>(rp1, colp1, valp1, Ts, (float*)d_out, N0);
}

// Round 9
// 1100.316 us; speedup vs baseline: 2.2395x; 1.0611x over previous
//
#include <hip/hip_runtime.h>
#include <hip/hip_bf16.h>
#include <stdint.h>

// ---------------------------------------------------------------------------
// PlanetoidSCN R9: binarize -> bitmask features -> binary SpMM (thread/nnz,
// set-bit loop) -> split-bf16 MFMA GEMMs -> CSR-gather SpMM -> combine.
//
// Workspace: S1 | S2 | Ts = 256,000,000 B exactly (known-safe from R6).
// Overlays (time-sliced, no new ws):
//   - Xb/Eb/Tb bit buffers in Ts head (dead once binary SpMMs done)
//   - B2 CSR + Wt/We/Wtri bf16 splits in d_out (S0 pipeline runs last)
//   - Xb2 + B1 CSR + Wn bf16 split in S2 region (dead after B2-gather)
// ---------------------------------------------------------------------------

typedef __attribute__((ext_vector_type(8))) short bf16x8;
typedef __attribute__((ext_vector_type(4))) float f32x4;

__device__ __forceinline__ short f2bf(float x) {
    __hip_bfloat16 h = __float2bfloat16(x);
    return *reinterpret_cast<short*>(&h);
}
__device__ __forceinline__ float bf2f(short s) {
    __hip_bfloat16 h = *reinterpret_cast<__hip_bfloat16*>(&s);
    return __bfloat162float(h);
}

__global__ __launch_bounds__(256) void k_bits_node(const float* __restrict__ X,
        ulonglong2* __restrict__ bits, int n)
{
    int wid = (blockIdx.x * 256 + threadIdx.x) >> 6;
    int lane = threadIdx.x & 63;
    if (wid >= n) return;
    const float* row = X + (size_t)wid * 128;
    unsigned long long m0 = __ballot(row[lane] != 0.0f);
    unsigned long long m1 = __ballot(row[lane + 64] != 0.0f);
    if (lane == 0) { bits[wid].x = m0; bits[wid].y = m1; }
}

__global__ __launch_bounds__(256) void k_bits_edge(const int* __restrict__ idx,
        const ulonglong2* __restrict__ nb, ulonglong2* __restrict__ outb, int n)
{
    int e = blockIdx.x * 256 + threadIdx.x;
    if (e >= n) return;
    ulonglong2 a = nb[idx[2 * e]];
    ulonglong2 b = nb[idx[2 * e + 1]];
    ulonglong2 r; r.x = a.x & b.x; r.y = a.y & b.y;
    outb[e] = r;
}

__global__ __launch_bounds__(256) void k_bits_tri(const int* __restrict__ idx,
        const ulonglong2* __restrict__ nb, ulonglong2* __restrict__ outb, int n)
{
    int e = blockIdx.x * 256 + threadIdx.x;
    if (e >= n) return;
    ulonglong2 a = nb[idx[3 * e]];
    ulonglong2 b = nb[idx[3 * e + 1]];
    ulonglong2 c = nb[idx[3 * e + 2]];
    ulonglong2 r; r.x = a.x & b.x & c.x; r.y = a.y & b.y & c.y;
    outb[e] = r;
}

// S[row] += val * bits(col): ONE THREAD per nnz, loop over set bits only.
// (R8's wave-per-nnz burned a 64-lane wave for ~1.3 active lanes.)
__global__ __launch_bounds__(256) void k_spmm_bin_t(const int* __restrict__ rows,
        const int* __restrict__ cols, const float* __restrict__ vals,
        const ulonglong2* __restrict__ bits, float* __restrict__ S, int nnz)
{
    int nz = blockIdx.x * 256 + threadIdx.x;
    if (nz >= nnz) return;
    int r = rows[nz], c = cols[nz];
    float v = vals[nz];
    ulonglong2 m = bits[c];
    float* out = S + (size_t)r * 128;
    unsigned long long mx = m.x;
    while (mx) {
        int b = __ffsll(mx) - 1;
        atomicAdd(out + b, v);
        mx &= mx - 1;
    }
    unsigned long long my = m.y;
    while (my) {
        int b = __ffsll(my) - 1;
        atomicAdd(out + 64 + b, v);
        my &= my - 1;
    }
}

// ---------------- CSR build: histogram -> scan -> scatter -------------------

__global__ __launch_bounds__(256) void k_hist(const int* __restrict__ rows,
        int* __restrict__ rp, int nnz)
{
    int nz = blockIdx.x * 256 + threadIdx.x;
    if (nz >= nnz) return;
    atomicAdd(&rp[rows[nz] + 1], 1);
}

__global__ __launch_bounds__(256) void k_scan_block(int* __restrict__ a, int n,
        int* __restrict__ bsum)
{
    __shared__ int sm[256];
    int b = blockIdx.x, t = threadIdx.x;
    int g = b * 1024 + t * 4;
    int x0 = (g + 0 < n) ? a[g + 0] : 0;
    int x1 = (g + 1 < n) ? a[g + 1] : 0;
    int x2 = (g + 2 < n) ? a[g + 2] : 0;
    int x3 = (g + 3 < n) ? a[g + 3] : 0;
    int ts = x0 + x1 + x2 + x3;
    sm[t] = ts; __syncthreads();
    for (int ofs = 1; ofs < 256; ofs <<= 1) {
        int x = (t >= ofs) ? sm[t - ofs] : 0;
        __syncthreads();
        sm[t] += x;
        __syncthreads();
    }
    int excl = sm[t] - ts;
    if (g + 0 < n) a[g + 0] = excl + x0;
    if (g + 1 < n) a[g + 1] = excl + x0 + x1;
    if (g + 2 < n) a[g + 2] = excl + x0 + x1 + x2;
    if (g + 3 < n) a[g + 3] = excl + ts;
    if (t == 255) bsum[b] = sm[255];
}

__global__ __launch_bounds__(256) void k_scan_top(int* __restrict__ bsum, int nb)
{
    __shared__ int sm[256];
    int t = threadIdx.x;
    int v = (t < nb) ? bsum[t] : 0;
    sm[t] = v; __syncthreads();
    for (int ofs = 1; ofs < 256; ofs <<= 1) {
        int x = (t >= ofs) ? sm[t - ofs] : 0;
        __syncthreads();
        sm[t] += x;
        __syncthreads();
    }
    if (t < nb) bsum[t] = sm[t] - v;   // exclusive
}

__global__ __launch_bounds__(256) void k_scan_add(int* __restrict__ a, int n,
        const int* __restrict__ bsum)
{
    int g = blockIdx.x * 256 + threadIdx.x;
    if (g >= n) return;
    a[g] += bsum[g >> 10];
}

__global__ __launch_bounds__(256) void k_scatter(const int* __restrict__ rows,
        const int* __restrict__ cols, const float* __restrict__ vals,
        int* __restrict__ rf, int* __restrict__ colp, float* __restrict__ valp,
        int nnz, float scale)
{
    int nz = blockIdx.x * 256 + threadIdx.x;
    if (nz >= nnz) return;
    int r = rows[nz];
    int pos = atomicAdd(&rf[r], 1);
    colp[pos] = cols[nz];
    valp[pos] = vals[nz] * scale;
}

// One wave per row: Out[r] = sum valp[i] * X[colp[i]]  (writes all rows).
__global__ __launch_bounds__(256) void k_gather_write(const int* __restrict__ rp,
        const int* __restrict__ colp, const float* __restrict__ valp,
        const float* __restrict__ X, float* __restrict__ Out, int nrows)
{
    int r = (blockIdx.x * 256 + threadIdx.x) >> 6;
    int lane = threadIdx.x & 63;
    if (r >= nrows) return;
    int s = rp[r], e = rp[r + 1];
    float2 acc = make_float2(0.f, 0.f);
    for (int i = s; i < e; ++i) {
        int c = colp[i];
        float v = valp[i];
        float2 x = *(const float2*)(X + (size_t)c * 128 + lane * 2);
        acc.x += v * x.x;
        acc.y += v * x.y;
    }
    *(float2*)(Out + (size_t)r * 128 + lane * 2) = acc;
}

// One wave per row: Out[r] += sum valp[i] * X[colp[i]]  (skip empty rows).
__global__ __launch_bounds__(256) void k_gather_add(const int* __restrict__ rp,
        const int* __restrict__ colp, const float* __restrict__ valp,
        const float* __restrict__ X, float* __restrict__ Out, int nrows)
{
    int r = (blockIdx.x * 256 + threadIdx.x) >> 6;
    int lane = threadIdx.x & 63;
    if (r >= nrows) return;
    int s = rp[r], e = rp[r + 1];
    if (s == e) return;
    float2 acc = make_float2(0.f, 0.f);
    for (int i = s; i < e; ++i) {
        int c = colp[i];
        float v = valp[i];
        float2 x = *(const float2*)(X + (size_t)c * 128 + lane * 2);
        acc.x += v * x.x;
        acc.y += v * x.y;
    }
    float* o = Out + (size_t)r * 128 + lane * 2;
    float2 cur = *(float2*)o;
    cur.x += acc.x; cur.y += acc.y;
    *(float2*)o = cur;
}

// Split f32 W -> bf16 hi + bf16 lo (RNE both stages).
__global__ __launch_bounds__(256) void k_wsplit(const float* __restrict__ W,
        short* __restrict__ hi, short* __restrict__ lo, int n)
{
    int i = blockIdx.x * 256 + threadIdx.x;
    if (i >= n) return;
    float x = W[i];
    short h = f2bf(x);
    hi[i] = h;
    lo[i] = f2bf(x - bf2f(h));
}

// ---------------------------------------------------------------------------
// Split-bf16 MFMA GEMM: H = epi(S @ W^T + b). W given pre-split (hi/lo bf16,
// row-major [128][128]). Block = 256 thr = 4 waves; tile = 64 rows x 128 cols.
// C ~= Shi*Whi + Shi*Wlo + Slo*Whi (f32 accum); |err| <~ 128*2^-18*|S||W|.
// ---------------------------------------------------------------------------
template<int PRELU, int ADDSRC>
__global__ __launch_bounds__(256) void k_gemm_mfma(const float* __restrict__ S,
        const short* __restrict__ Whi, const short* __restrict__ Wlo,
        const float* __restrict__ bias, const float* __restrict__ addsrc,
        const float* __restrict__ pw, float* __restrict__ H, int n_rows,
        float scale)
{
    __shared__ short Wh[128 * 136];
    __shared__ short Wl[128 * 136];
    const int t = threadIdx.x;

    const uint32_t* gh = (const uint32_t*)Whi;
    const uint32_t* gl = (const uint32_t*)Wlo;
    for (int i = t; i < 128 * 64; i += 256) {      // u32 = 2 bf16
        int r = i >> 6, cp = i & 63;
        *(uint32_t*)&Wh[r * 136 + cp * 2] = gh[r * 64 + cp];
        *(uint32_t*)&Wl[r * 136 + cp * 2] = gl[r * 64 + cp];
    }
    __syncthreads();

    const int wave = t >> 6, lane = t & 63;
    const int lm = lane & 15, kg = lane >> 4;
    const int band = blockIdx.x * 64 + wave * 16;
    const int row_a = band + lm;                   // A-operand row for this lane
    const bool arow_ok = row_a < n_rows;

    f32x4 acc[8];
#pragma unroll
    for (int ct = 0; ct < 8; ++ct) acc[ct] = (f32x4){0.f, 0.f, 0.f, 0.f};

    for (int ks = 0; ks < 4; ++ks) {
        const int k0 = ks * 32 + kg * 8;
        float a[8];
        if (arow_ok) {
            float4 v0 = *(const float4*)(S + (size_t)row_a * 128 + k0);
            float4 v1 = *(const float4*)(S + (size_t)row_a * 128 + k0 + 4);
            a[0]=v0.x; a[1]=v0.y; a[2]=v0.z; a[3]=v0.w;
            a[4]=v1.x; a[5]=v1.y; a[6]=v1.z; a[7]=v1.w;
        } else {
#pragma unroll
            for (int i = 0; i < 8; ++i) a[i] = 0.f;
        }
        bf16x8 ahi, alo;
#pragma unroll
        for (int i = 0; i < 8; ++i) {
            short h = f2bf(a[i]);
            ahi[i] = h;
            alo[i] = f2bf(a[i] - bf2f(h));
        }
#pragma unroll
        for (int ct = 0; ct < 8; ++ct) {
            const int brow = ct * 16 + lm;
            bf16x8 bhi = *(const bf16x8*)&Wh[brow * 136 + k0];
            bf16x8 blo = *(const bf16x8*)&Wl[brow * 136 + k0];
            acc[ct] = __builtin_amdgcn_mfma_f32_16x16x32_bf16(ahi, bhi, acc[ct], 0, 0, 0);
            acc[ct] = __builtin_amdgcn_mfma_f32_16x16x32_bf16(ahi, blo, acc[ct], 0, 0, 0);
            acc[ct] = __builtin_amdgcn_mfma_f32_16x16x32_bf16(alo, bhi, acc[ct], 0, 0, 0);
        }
    }

    // C/D: col = ct*16 + (lane&15), row = band + (lane>>4)*4 + j
    const int r0 = band + kg * 4;
    float w = 0.f;
    if (PRELU) w = pw[0];
#pragma unroll
    for (int ct = 0; ct < 8; ++ct) {
        const int col = ct * 16 + lm;
        const float b = bias[col];
#pragma unroll
        for (int j = 0; j < 4; ++j) {
            const int row = r0 + j;
            if (row >= n_rows) continue;
            float x = acc[ct][j] + b;
            if (PRELU) x = x >= 0.f ? x : w * x;
            x *= scale;
            if (ADDSRC) x += addsrc[(size_t)row * 128 + col];
            H[(size_t)row * 128 + col] = x;
        }
    }
}

extern "C" void kernel_launch(void* const* d_in, const int* in_sizes, int n_in,
                              void* d_out, int out_size, void* d_ws, size_t ws_size,
                              hipStream_t stream)
{
    const float* X0  = (const float*)d_in[0];
    const int*  eidx = (const int*)  d_in[1];
    const int*  tidx = (const int*)  d_in[2];
    const int* L0r = (const int*)d_in[3];
    const int* L0c = (const int*)d_in[4];
    const float* L0v = (const float*)d_in[5];
    const int* L1r = (const int*)d_in[6];
    const int* L1c = (const int*)d_in[7];
    const float* L1v = (const float*)d_in[8];
    const int* L2r = (const int*)d_in[9];
    const int* L2c = (const int*)d_in[10];
    const float* L2v = (const float*)d_in[11];
    const int* B1r = (const int*)d_in[12];
    const int* B1c = (const int*)d_in[13];
    const float* B1v = (const float*)d_in[14];
    const int* B2r = (const int*)d_in[15];
    const int* B2c = (const int*)d_in[16];
    const float* B2v = (const float*)d_in[17];
    const float* Wn   = (const float*)d_in[18];
    const float* bn   = (const float*)d_in[19];
    const float* We   = (const float*)d_in[20];
    const float* be   = (const float*)d_in[21];
    const float* Wt   = (const float*)d_in[22];
    const float* bt   = (const float*)d_in[23];
    const float* Wtri = (const float*)d_in[24];
    const float* btri = (const float*)d_in[25];
    const float* pw   = (const float*)d_in[26];

    const int N0 = in_sizes[0] / 128;
    const int N1 = in_sizes[1] / 2;
    const int N2 = in_sizes[2] / 3;
    const int nnz0 = in_sizes[3], nnz1 = in_sizes[6], nnz2 = in_sizes[9];
    const int nnzb1 = in_sizes[12], nnzb2 = in_sizes[15];

    // --- base workspace: S1 | S2 | Ts = 256,000,000 B exactly ---
    char* ws = (char*)d_ws;
    size_t off = 0;
    auto take = [&](size_t bytes) {
        void* p = ws + off;
        off += (bytes + 255) & ~(size_t)255;
        return p;
    };
    float* S1 = (float*)take((size_t)N1 * 512);
    float* S2 = (float*)take((size_t)N2 * 512);
    float* Ts = (float*)take((size_t)N1 * 512);

    // bit buffers overlay Ts head (dead before Ts first written)
    ulonglong2* Xb = (ulonglong2*)Ts;
    ulonglong2* Eb = (ulonglong2*)((char*)Ts + (size_t)N0 * 16);
    ulonglong2* Tb = (ulonglong2*)((char*)Ts + (size_t)(N0 + N1) * 16);

    // B2 CSR + Wt/We/Wtri splits overlay d_out (S0 pipeline runs last)
    auto align256 = [](size_t x) { return (x + 255) & ~(size_t)255; };
    char* dob = (char*)d_out;
    size_t doff = 0;
    int*   rp2   = (int*)(dob + doff); doff += align256((size_t)(N1 + 1) * 4);
    int*   rf2   = (int*)(dob + doff); doff += align256((size_t)(N1 + 1) * 4);
    int*   colp2 = (int*)(dob + doff); doff += align256((size_t)nnzb2 * 4);
    float* valp2 = (float*)(dob + doff); doff += align256((size_t)nnzb2 * 4);
    int*   bsum2 = (int*)(dob + doff); doff += 1024;
    short* WThi  = (short*)(dob + doff); doff += 32768;   // 128*128*2 B each
    short* WTlo  = (short*)(dob + doff); doff += 32768;
    short* WEhi  = (short*)(dob + doff); doff += 32768;
    short* WElo  = (short*)(dob + doff); doff += 32768;
    short* WRhi  = (short*)(dob + doff); doff += 32768;
    short* WRlo  = (short*)(dob + doff); doff += 32768;

    // B1 CSR + node bits + Wn split overlay S2 (dead after B2-gather)
    char* s2b = (char*)S2;
    size_t soff = 0;
    ulonglong2* Xb2 = (ulonglong2*)(s2b + soff); soff += align256((size_t)N0 * 16);
    int*   rp1   = (int*)(s2b + soff); soff += align256((size_t)(N0 + 1) * 4);
    int*   rf1   = (int*)(s2b + soff); soff += align256((size_t)(N0 + 1) * 4);
    int*   colp1 = (int*)(s2b + soff); soff += align256((size_t)nnzb1 * 4);
    float* valp1 = (float*)(s2b + soff); soff += align256((size_t)nnzb1 * 4);
    int*   bsum1 = (int*)(s2b + soff); soff += 1024;
    short* WNhi  = (short*)(s2b + soff); soff += 32768;
    short* WNlo  = (short*)(s2b + soff); soff += 32768;

    dim3 blk(256);

    // --- phase A: bits + binary SpMMs into S1/S2 ---
    hipMemsetAsync(S1, 0, (size_t)N1 * 512, stream);
    hipMemsetAsync(S2, 0, (size_t)N2 * 512, stream);
    k_bits_node<<<(N0 + 3) / 4, blk, 0, stream>>>(X0, Xb, N0);
    k_bits_edge<<<(N1 + 255) / 256, blk, 0, stream>>>(eidx, Xb, Eb, N1);
    k_bits_tri<<<(N2 + 255) / 256, blk, 0, stream>>>(tidx, Xb, Tb, N2);
    k_spmm_bin_t<<<(nnz1 + 255) / 256, blk, 0, stream>>>(L1r, L1c, L1v, Eb, S1, nnz1);
    k_spmm_bin_t<<<(nnz2 + 255) / 256, blk, 0, stream>>>(L2r, L2c, L2v, Tb, S2, nnz2);

    // --- weight splits (d_out overlay) ---
    k_wsplit<<<64, blk, 0, stream>>>(Wt,   WThi, WTlo, 16384);
    k_wsplit<<<64, blk, 0, stream>>>(We,   WEhi, WElo, 16384);
    k_wsplit<<<64, blk, 0, stream>>>(Wtri, WRhi, WRlo, 16384);

    // --- B2 CSR build (d_out overlay) ---
    {
        int n = N1 + 1;
        int nb = (n + 1023) / 1024;
        hipMemsetAsync(rp2, 0, (size_t)n * 4, stream);
        k_hist<<<(nnzb2 + 255) / 256, blk, 0, stream>>>(B2r, rp2, nnzb2);
        k_scan_block<<<nb, blk, 0, stream>>>(rp2, n, bsum2);
        k_scan_top<<<1, blk, 0, stream>>>(bsum2, nb);
        k_scan_add<<<(n + 255) / 256, blk, 0, stream>>>(rp2, n, bsum2);
        hipMemcpyAsync(rf2, rp2, (size_t)n * 4, hipMemcpyDeviceToDevice, stream);
        k_scatter<<<(nnzb2 + 255) / 256, blk, 0, stream>>>(B2r, B2c, B2v, rf2,
                colp2, valp2, nnzb2, 1.0f);
    }

    // --- H2 = prelu(S2 @ Wt^T + bt) (in place, MFMA) ---
    k_gemm_mfma<1, 0><<<(N2 + 63) / 64, blk, 0, stream>>>(S2, WThi, WTlo, bt,
            nullptr, pw, S2, N2, 1.0f);
    // --- H1 = prelu(S1 @ We^T + be) (in place, MFMA; before Ts clobber) ---
    k_gemm_mfma<1, 0><<<(N1 + 63) / 64, blk, 0, stream>>>(S1, WEhi, WElo, be,
            nullptr, pw, S1, N1, 1.0f);
    // --- Ts = B2 @ H2 (gather; writes every row, clobbers bit overlay) ---
    k_gather_write<<<(N1 + 3) / 4, blk, 0, stream>>>(rp2, colp2, valp2, S2, Ts, N1);
    // --- U = (Ts @ Wtri^T + btri) + H1 (in place over Ts; S1 dies after) ---
    k_gemm_mfma<0, 1><<<(N1 + 63) / 64, blk, 0, stream>>>(Ts, WRhi, WRlo, btri,
            S1, pw, Ts, N1, 1.0f);

    // --- phase B: S2 region now free -> node bits + B1 CSR + Wn split ---
    k_bits_node<<<(N0 + 3) / 4, blk, 0, stream>>>(X0, Xb2, N0);
    k_wsplit<<<64, blk, 0, stream>>>(Wn, WNhi, WNlo, 16384);
    {
        int n = N0 + 1;
        int nb = (n + 1023) / 1024;
        hipMemsetAsync(rp1, 0, (size_t)n * 4, stream);
        k_hist<<<(nnzb1 + 255) / 256, blk, 0, stream>>>(B1r, rp1, nnzb1);
        k_scan_block<<<nb, blk, 0, stream>>>(rp1, n, bsum1);
        k_scan_top<<<1, blk, 0, stream>>>(bsum1, nb);
        k_scan_add<<<(n + 255) / 256, blk, 0, stream>>>(rp1, n, bsum1);
        hipMemcpyAsync(rf1, rp1, (size_t)n * 4, hipMemcpyDeviceToDevice, stream);
        k_scatter<<<(nnzb1 + 255) / 256, blk, 0, stream>>>(B1r, B1c, B1v, rf1,
                colp1, valp1, nnzb1, 1.0f / 3.0f);
    }

    // --- S0 pipeline (d_out region now free of B2 CSR + W splits) ---
    hipMemsetAsync(d_out, 0, (size_t)N0 * 512, stream);
    k_spmm_bin_t<<<(nnz0 + 255) / 256, blk, 0, stream>>>(L0r, L0c, L0v, Xb2, (float*)d_out, nnz0);
    // d_out = prelu(S0 @ Wn^T + bn) / 3   (in place, MFMA)
    k_gemm_mfma<1, 0><<<(N0 + 63) / 64, blk, 0, stream>>>((float*)d_out, WNhi, WNlo,
            bn, nullptr, pw, (float*)d_out, N0, 1.0f / 3.0f);
    // d_out += B1 @ U (valp1 pre-scaled by 1/3; non-atomic, one wave per row)
    k_gather_add<<<(N0 + 3) / 4, blk, 0, stream>>>(rp1, colp1, valp1, Ts, (float*)d_out, N0);
}